// Round 6
// baseline (134.976 us; speedup 1.0000x reference)
//
#include <hip/hip_runtime.h>

#define NQ   13
#define DIM  8192
#define NT   512     // 8 waves/block; 2 blocks/CU -> 4 waves/SIMD
#define NAMP 16      // amplitudes per thread (4-bit register window)
#define PI_F 3.14159265358979323846f

// LDS slot padding: +1 float per 32 -> <=2-way bank aliasing (free) everywhere
__device__ __forceinline__ int lslot(int i) { return i + (i >> 5); }
#define NSLOT (DIM + (DIM >> 5))   // 8448 floats per component

// range-reduced fast sincos
__device__ __forceinline__ void rsincos(float x, float* s, float* c) {
  const float INV2PI = 0.15915494309189535f;
  const float TWOPI  = 6.283185307179586f;
  float r = x * INV2PI;
  r -= rintf(r);
  float ang = r * TWOPI;
  *s = __sinf(ang);
  *c = __cosf(ang);
}

// ---------------------------------------------------------------------------
// 4-bit window patterns. W[k] = i-bit of register bit k; N[k] = i-bit of t-bit k.
// ---------------------------------------------------------------------------
template<int P> struct Pat;
template<> struct Pat<0> { static constexpr int W[4] = {0,1,2,3};
  static constexpr int N[9] = {4,5,6,7,8,9,10,11,12};
  static __device__ __forceinline__ int idx(int t, int j) { return (t << 4) | j; } };
template<> struct Pat<1> { static constexpr int W[4] = {4,5,6,7};
  static constexpr int N[9] = {0,1,2,3,8,9,10,11,12};
  static __device__ __forceinline__ int idx(int t, int j) { return ((t >> 4) << 8) | (j << 4) | (t & 15); } };
template<> struct Pat<2> { static constexpr int W[4] = {8,9,10,11};
  static constexpr int N[9] = {0,1,2,3,4,5,6,7,12};
  static __device__ __forceinline__ int idx(int t, int j) { return ((t >> 8) << 12) | (j << 8) | (t & 255); } };
template<> struct Pat<3> { static constexpr int W[4] = {0,1,2,12};
  static constexpr int N[9] = {3,4,5,6,7,8,9,10,11};
  static __device__ __forceinline__ int idx(int t, int j) { return ((j & 8) << 9) | (t << 3) | (j & 7); } };
template<> struct Pat<4> { static constexpr int W[4] = {3,4,5,6};
  static constexpr int N[9] = {0,1,2,7,8,9,10,11,12};
  static __device__ __forceinline__ int idx(int t, int j) { return ((t >> 3) << 7) | (j << 3) | (t & 7); } };
template<> struct Pat<5> { static constexpr int W[4] = {7,8,9,10};
  static constexpr int N[9] = {0,1,2,3,4,5,6,11,12};
  static __device__ __forceinline__ int idx(int t, int j) { return ((t >> 7) << 11) | (j << 7) | (t & 127); } };
template<> struct Pat<6> { static constexpr int W[4] = {0,1,2,11};
  static constexpr int N[9] = {3,4,5,6,7,8,9,10,12};
  static __device__ __forceinline__ int idx(int t, int j) { return ((t & 256) << 4) | ((j & 8) << 8) | ((t & 255) << 3) | (j & 7); } };

template<int P>
__device__ __forceinline__ void loadAmps(const float* __restrict__ sRe,
                                         const float* __restrict__ sIm,
                                         int t, float* re, float* im) {
  #pragma unroll
  for (int j = 0; j < NAMP; j++) {
    int a = lslot(Pat<P>::idx(t, j));
    re[j] = sRe[a]; im[j] = sIm[a];
  }
}
template<int P>
__device__ __forceinline__ void storeAmps(float* __restrict__ sRe,
                                          float* __restrict__ sIm,
                                          int t, const float* re, const float* im) {
  #pragma unroll
  for (int j = 0; j < NAMP; j++) {
    int a = lslot(Pat<P>::idx(t, j));
    sRe[a] = re[j]; sIm[a] = im[j];
  }
}

// s[j] = bias + sum over set i-bits of w[bitpos]
template<int P>
__device__ __forceinline__ void buildTree(const float* __restrict__ w, float bias,
                                          int t, float* s) {
  float base = bias;
  #pragma unroll
  for (int k = 0; k < 9; k++) base += ((t >> k) & 1) ? w[Pat<P>::N[k]] : 0.0f;
  s[0] = base;
  #pragma unroll
  for (int k = 0; k < 4; k++) {
    float wp = w[Pat<P>::W[k]];
    #pragma unroll
    for (int m = 0; m < (1 << k); m++) s[m | (1 << k)] = s[m] + wp;
  }
}

template<int KB>
__device__ __forceinline__ void fwht_bit(float* re, float* im) {
  #pragma unroll
  for (int j = 0; j < NAMP; j++) if (!(j & (1 << KB))) {
    int j1 = j | (1 << KB);
    float r0 = re[j], i0 = im[j], r1 = re[j1], i1 = im[j1];
    re[j]  = r0 + r1; im[j]  = i0 + i1;
    re[j1] = r0 - r1; im[j1] = i0 - i1;
  }
}
__device__ __forceinline__ void fwht_all4(float* re, float* im) {
  fwht_bit<0>(re, im); fwht_bit<1>(re, im); fwht_bit<2>(re, im); fwht_bit<3>(re, im);
}

template<int KB>
__device__ __forceinline__ void applyRy(float* re, float* im, float ca, float sa) {
  #pragma unroll
  for (int j = 0; j < NAMP; j++) if (!(j & (1 << KB))) {
    int j1 = j | (1 << KB);
    float r0 = re[j], i0 = im[j], r1 = re[j1], i1 = im[j1];
    re[j]  = ca * r0 - sa * r1;  im[j]  = ca * i0 - sa * i1;
    re[j1] = sa * r0 + ca * r1;  im[j1] = sa * i0 + ca * i1;
  }
}

// Ry of layer l on register bit KB (targets i-bit W[KB], qubit q = 12 - W[KB])
template<int P, int KB>
__device__ __forceinline__ void ryOn(float* re, float* im,
                                     const float* __restrict__ gCA,
                                     const float* __restrict__ gSA, int l) {
  constexpr int q = 12 - Pat<P>::W[KB];
  int g = l * NQ + q;
  applyRy<KB>(re, im, gCA[g], gSA[g]);
}
template<int P>
__device__ __forceinline__ void ry4(float* re, float* im,
                                    const float* __restrict__ gCA,
                                    const float* __restrict__ gSA, int l) {
  ryOn<P, 0>(re, im, gCA, gSA, l);
  ryOn<P, 1>(re, im, gCA, gSA, l);
  ryOn<P, 2>(re, im, gCA, gSA, l);
  ryOn<P, 3>(re, im, gCA, gSA, l);
}

// psi *= exp(i*phi(i)) with phi = u + 0.5*(v^2 - A2); INIT=true writes instead
template<int P, bool INIT>
__device__ __forceinline__ void featureDiag(float* re, float* im,
                                            const float* __restrict__ wX,
                                            const float* __restrict__ wA,
                                            const float* __restrict__ cons, int t) {
  float u[NAMP], v[NAMP];
  buildTree<P>(wX, cons[0], t, u);
  buildTree<P>(wA, cons[1], t, v);
  float A2 = cons[2];
  #pragma unroll
  for (int j = 0; j < NAMP; j++) {
    float phi = u[j] + 0.5f * (v[j] * v[j] - A2);
    float sn, cs; rsincos(phi, &sn, &cs);
    if constexpr (INIT) { re[j] = cs; im[j] = sn; }
    else {
      float r = re[j], q = im[j];
      re[j] = r * cs - q * sn;
      im[j] = r * sn + q * cs;
    }
  }
}

// psi *= ENT(i) * exp(i*rho(i)); rho linear in bits -> complex product tree
template<int P>
__device__ __forceinline__ void applyDiag(float* re, float* im,
                                          const float* __restrict__ wb,   // b by bitpos (layer slice)
                                          const float* __restrict__ eR,   // cos(b) by bitpos (layer slice)
                                          const float* __restrict__ eI,   // sin(b) by bitpos
                                          float bias, int t) {
  float base = bias;
  #pragma unroll
  for (int k = 0; k < 9; k++) base += ((t >> k) & 1) ? wb[Pat<P>::N[k]] : 0.0f;
  float cR[NAMP], cI[NAMP];
  rsincos(base, &cI[0], &cR[0]);
  #pragma unroll
  for (int k = 0; k < 4; k++) {
    float er = eR[Pat<P>::W[k]], ei = eI[Pat<P>::W[k]];
    #pragma unroll
    for (int m = 0; m < (1 << k); m++) {
      float r0 = cR[m], i0 = cI[m];
      cR[m | (1 << k)] = r0 * er - i0 * ei;
      cI[m | (1 << k)] = r0 * ei + i0 * er;
    }
  }
  #pragma unroll
  for (int j = 0; j < NAMP; j++) {
    int i = Pat<P>::idx(t, j);
    float sgn = (__popc(i & (i >> 1)) & 1) ? -1.0f : 1.0f;
    float cs = cR[j] * sgn, sn = cI[j] * sgn;
    float r = re[j], q = im[j];
    re[j] = r * cs - q * sn;
    im[j] = r * sn + q * cs;
  }
}

__global__ __launch_bounds__(NT, 4) void qc_kernel(
    const float* __restrict__ xin,
    const float* __restrict__ thin,
    const float* __restrict__ bin,
    float* __restrict__ out) {
  __shared__ float sRe[NSLOT];
  __shared__ float sIm[NSLOT];
  __shared__ float gCA[65], gSA[65];     // cos/sin(a/2), index l*13+q
  __shared__ float gBbit[65];            // b by [l*13 + bitpos], bitpos p = 12-q
  __shared__ float eBr[65], eBi[65];     // cos(b), sin(b) by [l*13 + bitpos]
  __shared__ float wX[13], wA[13];       // -2x, -2a by bitpos
  __shared__ float cons[8];              // 0:sumX 1:sumA 2:sumA2 3..7:-0.5*sum b_l
  __shared__ float red[NT / 64];

  const int t = threadIdx.x;
  const int b = blockIdx.x;

  if (t < NQ) {
    float xq = xin[b * NQ + t];
    float aq = PI_F - xq;
    wX[12 - t] = -2.0f * xq;
    wA[12 - t] = -2.0f * aq;
  }
  if (t < 65) {
    float av = thin[2 * t];
    float bv = thin[2 * t + 1];
    gCA[t] = cosf(0.5f * av);
    gSA[t] = sinf(0.5f * av);
    int l = t / NQ, q = t % NQ;
    int s = l * NQ + (12 - q);
    gBbit[s] = bv;
    eBr[s] = cosf(bv);
    eBi[s] = sinf(bv);
  }
  __syncthreads();
  if (t == 0) {
    float X = 0.f, A = 0.f, A2 = 0.f;
    for (int p = 0; p < NQ; p++) {
      float xq = -0.5f * wX[p], aq = -0.5f * wA[p];
      X += xq; A += aq; A2 += aq * aq;
    }
    cons[0] = X; cons[1] = A; cons[2] = A2;
    for (int l = 0; l < 5; l++) {
      float s = 0.f;
      for (int p = 0; p < NQ; p++) s += gBbit[l * NQ + p];
      cons[3 + l] = -0.5f * s;
    }
  }
  __syncthreads();

  float re[NAMP], im[NAMP];

  // P0 (pat0): init psi = exp(i*phi); FWHT bits 0-3
  featureDiag<0, true>(re, im, wX, wA, cons, t);
  fwht_all4(re, im);
  storeAmps<0>(sRe, sIm, t, re, im);
  __syncthreads();

  // P1 (pat1): FWHT bits 4-7
  loadAmps<1>(sRe, sIm, t, re, im);
  fwht_all4(re, im);
  storeAmps<1>(sRe, sIm, t, re, im);
  __syncthreads();

  // P2 (pat2): FWHT bits 8-11
  loadAmps<2>(sRe, sIm, t, re, im);
  fwht_all4(re, im);
  storeAmps<2>(sRe, sIm, t, re, im);
  __syncthreads();

  // P3 (pat3): FWHT bit 12; second feature diag; L0 gates on i-bits {0,1,2,12}
  loadAmps<3>(sRe, sIm, t, re, im);
  fwht_bit<3>(re, im);
  featureDiag<3, false>(re, im, wX, wA, cons, t);
  ry4<3>(re, im, gCA, gSA, 0);
  storeAmps<3>(sRe, sIm, t, re, im);
  __syncthreads();

  float acc = 0.0f;
  // layer loop: transitions at patterns alternating 6 (bit 11) and 3 (bit 12)
  #pragma unroll 1
  for (int l = 0; l < 5; l++) {
    // mid pass 1 (pat4): gates on i-bits {3,4,5,6}
    loadAmps<4>(sRe, sIm, t, re, im);
    ry4<4>(re, im, gCA, gSA, l);
    storeAmps<4>(sRe, sIm, t, re, im);
    __syncthreads();
    // mid pass 2 (pat5): gates on i-bits {7,8,9,10}
    loadAmps<5>(sRe, sIm, t, re, im);
    ry4<5>(re, im, gCA, gSA, l);
    storeAmps<5>(sRe, sIm, t, re, im);
    __syncthreads();
    // transition pass: finish layer l (leftover bit), diag l, start layer l+1
    if (l == 4) {
      // P18 (pat6): L4 on i-bit 11 (q=1) + readout
      loadAmps<6>(sRe, sIm, t, re, im);
      ryOn<6, 3>(re, im, gCA, gSA, 4);
      #pragma unroll
      for (int j = 0; j < NAMP; j++) {
        int i = Pat<6>::idx(t, j);
        float p2 = re[j] * re[j] + im[j] * im[j];
        acc += (__popc(i) & 1) ? -p2 : p2;
      }
    } else if ((l & 1) == 0) {
      // pat6: L_l on i-bit 11, diag l, L_{l+1} on {0,1,2,11}
      loadAmps<6>(sRe, sIm, t, re, im);
      ryOn<6, 3>(re, im, gCA, gSA, l);
      applyDiag<6>(re, im, gBbit + l * NQ, eBr + l * NQ, eBi + l * NQ, cons[3 + l], t);
      ry4<6>(re, im, gCA, gSA, l + 1);
      storeAmps<6>(sRe, sIm, t, re, im);
      __syncthreads();
    } else {
      // pat3: L_l on i-bit 12, diag l, L_{l+1} on {0,1,2,12}
      loadAmps<3>(sRe, sIm, t, re, im);
      ryOn<3, 3>(re, im, gCA, gSA, l);
      applyDiag<3>(re, im, gBbit + l * NQ, eBr + l * NQ, eBi + l * NQ, cons[3 + l], t);
      ry4<3>(re, im, gCA, gSA, l + 1);
      storeAmps<3>(sRe, sIm, t, re, im);
      __syncthreads();
    }
  }

  // block reduction (raw scale 2^26)
  #pragma unroll
  for (int off = 32; off > 0; off >>= 1) acc += __shfl_down(acc, off, 64);
  if ((t & 63) == 0) red[t >> 6] = acc;
  __syncthreads();
  if (t == 0) {
    float total = 0.f;
    #pragma unroll
    for (int w = 0; w < NT / 64; w++) total += red[w];
    float logit = total * (1.0f / 67108864.0f) + bin[0];
    out[b * 2 + 0] = -logit;
    out[b * 2 + 1] = logit;
  }
}

extern "C" void kernel_launch(void* const* d_in, const int* in_sizes, int n_in,
                              void* d_out, int out_size, void* d_ws, size_t ws_size,
                              hipStream_t stream) {
  const float* x  = (const float*)d_in[0];
  const float* th = (const float*)d_in[1];
  const float* bi = (const float*)d_in[2];
  float* out = (float*)d_out;
  int B = in_sizes[0] / NQ;   // 512
  qc_kernel<<<B, NT, 0, stream>>>(x, th, bi, out);
}

// Round 7
// 116.976 us; speedup vs baseline: 1.1539x; 1.1539x over previous
//
#include <hip/hip_runtime.h>

#define NQ   13
#define DIM  8192
#define NT   512     // 8 waves/block; 2 blocks/CU -> 4 waves/SIMD
#define NAMP 16      // amplitudes per thread (4-bit register window)
#define PI_F 3.14159265358979323846f

// LDS slot padding: +1 float per 32 -> <=2-way bank aliasing (free) everywhere
__device__ __forceinline__ int lslot(int i) { return i + (i >> 5); }
#define NSLOT (DIM + (DIM >> 5))   // 8448 floats per component

// range-reduced fast sincos
__device__ __forceinline__ void rsincos(float x, float* s, float* c) {
  const float INV2PI = 0.15915494309189535f;
  const float TWOPI  = 6.283185307179586f;
  float r = x * INV2PI;
  r -= rintf(r);
  float ang = r * TWOPI;
  *s = __sinf(ang);
  *c = __cosf(ang);
}

// ---------------------------------------------------------------------------
// 4-bit window patterns. W[k] = i-bit of register bit k; N[k] = i-bit of t-bit k.
// ---------------------------------------------------------------------------
template<int P> struct Pat;
template<> struct Pat<0> { static constexpr int W[4] = {0,1,2,3};
  static constexpr int N[9] = {4,5,6,7,8,9,10,11,12};
  static __device__ __forceinline__ int idx(int t, int j) { return (t << 4) | j; } };
template<> struct Pat<1> { static constexpr int W[4] = {4,5,6,7};
  static constexpr int N[9] = {0,1,2,3,8,9,10,11,12};
  static __device__ __forceinline__ int idx(int t, int j) { return ((t >> 4) << 8) | (j << 4) | (t & 15); } };
template<> struct Pat<2> { static constexpr int W[4] = {8,9,10,11};
  static constexpr int N[9] = {0,1,2,3,4,5,6,7,12};
  static __device__ __forceinline__ int idx(int t, int j) { return ((t >> 8) << 12) | (j << 8) | (t & 255); } };
template<> struct Pat<3> { static constexpr int W[4] = {0,1,2,12};
  static constexpr int N[9] = {3,4,5,6,7,8,9,10,11};
  static __device__ __forceinline__ int idx(int t, int j) { return ((j & 8) << 9) | (t << 3) | (j & 7); } };
template<> struct Pat<4> { static constexpr int W[4] = {3,4,5,6};
  static constexpr int N[9] = {0,1,2,7,8,9,10,11,12};
  static __device__ __forceinline__ int idx(int t, int j) { return ((t >> 3) << 7) | (j << 3) | (t & 7); } };
template<> struct Pat<5> { static constexpr int W[4] = {7,8,9,10};
  static constexpr int N[9] = {0,1,2,3,4,5,6,11,12};
  static __device__ __forceinline__ int idx(int t, int j) { return ((t >> 7) << 11) | (j << 7) | (t & 127); } };
template<> struct Pat<6> { static constexpr int W[4] = {0,1,2,11};
  static constexpr int N[9] = {3,4,5,6,7,8,9,10,12};
  static __device__ __forceinline__ int idx(int t, int j) { return ((t & 256) << 4) | ((j & 8) << 8) | ((t & 255) << 3) | (j & 7); } };

template<int P>
__device__ __forceinline__ void loadAmps(const float* __restrict__ sRe,
                                         const float* __restrict__ sIm,
                                         int t, float* re, float* im) {
  #pragma unroll
  for (int j = 0; j < NAMP; j++) {
    int a = lslot(Pat<P>::idx(t, j));
    re[j] = sRe[a]; im[j] = sIm[a];
  }
}
template<int P>
__device__ __forceinline__ void storeAmps(float* __restrict__ sRe,
                                          float* __restrict__ sIm,
                                          int t, const float* re, const float* im) {
  #pragma unroll
  for (int j = 0; j < NAMP; j++) {
    int a = lslot(Pat<P>::idx(t, j));
    sRe[a] = re[j]; sIm[a] = im[j];
  }
}

// s[j] = bias + sum over set i-bits of w[bitpos]
template<int P>
__device__ __forceinline__ void buildTree(const float* __restrict__ w, float bias,
                                          int t, float* s) {
  float base = bias;
  #pragma unroll
  for (int k = 0; k < 9; k++) base += ((t >> k) & 1) ? w[Pat<P>::N[k]] : 0.0f;
  s[0] = base;
  #pragma unroll
  for (int k = 0; k < 4; k++) {
    float wp = w[Pat<P>::W[k]];
    #pragma unroll
    for (int m = 0; m < (1 << k); m++) s[m | (1 << k)] = s[m] + wp;
  }
}

template<int KB>
__device__ __forceinline__ void fwht_bit(float* re, float* im) {
  #pragma unroll
  for (int j = 0; j < NAMP; j++) if (!(j & (1 << KB))) {
    int j1 = j | (1 << KB);
    float r0 = re[j], i0 = im[j], r1 = re[j1], i1 = im[j1];
    re[j]  = r0 + r1; im[j]  = i0 + i1;
    re[j1] = r0 - r1; im[j1] = i0 - i1;
  }
}
__device__ __forceinline__ void fwht_all4(float* re, float* im) {
  fwht_bit<0>(re, im); fwht_bit<1>(re, im); fwht_bit<2>(re, im); fwht_bit<3>(re, im);
}

template<int KB>
__device__ __forceinline__ void applyRy(float* re, float* im, float ca, float sa) {
  #pragma unroll
  for (int j = 0; j < NAMP; j++) if (!(j & (1 << KB))) {
    int j1 = j | (1 << KB);
    float r0 = re[j], i0 = im[j], r1 = re[j1], i1 = im[j1];
    re[j]  = ca * r0 - sa * r1;  im[j]  = ca * i0 - sa * i1;
    re[j1] = sa * r0 + ca * r1;  im[j1] = sa * i0 + ca * i1;
  }
}

// Ry of layer l on register bit KB (targets i-bit W[KB], qubit q = 12 - W[KB])
template<int P, int KB>
__device__ __forceinline__ void ryOn(float* re, float* im,
                                     const float* __restrict__ gCA,
                                     const float* __restrict__ gSA, int l) {
  constexpr int q = 12 - Pat<P>::W[KB];
  int g = l * NQ + q;
  applyRy<KB>(re, im, gCA[g], gSA[g]);
}
template<int P>
__device__ __forceinline__ void ry4(float* re, float* im,
                                    const float* __restrict__ gCA,
                                    const float* __restrict__ gSA, int l) {
  ryOn<P, 0>(re, im, gCA, gSA, l);
  ryOn<P, 1>(re, im, gCA, gSA, l);
  ryOn<P, 2>(re, im, gCA, gSA, l);
  ryOn<P, 3>(re, im, gCA, gSA, l);
}

// psi *= exp(i*phi(i)) with phi = u + 0.5*(v^2 - A2); INIT=true writes instead
template<int P, bool INIT>
__device__ __forceinline__ void featureDiag(float* re, float* im,
                                            const float* __restrict__ wX,
                                            const float* __restrict__ wA,
                                            const float* __restrict__ cons, int t) {
  float u[NAMP], v[NAMP];
  buildTree<P>(wX, cons[0], t, u);
  buildTree<P>(wA, cons[1], t, v);
  float A2 = cons[2];
  #pragma unroll
  for (int j = 0; j < NAMP; j++) {
    float phi = u[j] + 0.5f * (v[j] * v[j] - A2);
    float sn, cs; rsincos(phi, &sn, &cs);
    if constexpr (INIT) { re[j] = cs; im[j] = sn; }
    else {
      float r = re[j], q = im[j];
      re[j] = r * cs - q * sn;
      im[j] = r * sn + q * cs;
    }
  }
}

// psi *= ENT(i) * exp(i*rho(i)); rho linear in bits -> complex product tree
template<int P>
__device__ __forceinline__ void applyDiag(float* re, float* im,
                                          const float* __restrict__ wb,   // b by bitpos (layer slice)
                                          const float* __restrict__ eR,   // cos(b) by bitpos (layer slice)
                                          const float* __restrict__ eI,   // sin(b) by bitpos
                                          float bias, int t) {
  float base = bias;
  #pragma unroll
  for (int k = 0; k < 9; k++) base += ((t >> k) & 1) ? wb[Pat<P>::N[k]] : 0.0f;
  float cR[NAMP], cI[NAMP];
  rsincos(base, &cI[0], &cR[0]);
  #pragma unroll
  for (int k = 0; k < 4; k++) {
    float er = eR[Pat<P>::W[k]], ei = eI[Pat<P>::W[k]];
    #pragma unroll
    for (int m = 0; m < (1 << k); m++) {
      float r0 = cR[m], i0 = cI[m];
      cR[m | (1 << k)] = r0 * er - i0 * ei;
      cI[m | (1 << k)] = r0 * ei + i0 * er;
    }
  }
  #pragma unroll
  for (int j = 0; j < NAMP; j++) {
    int i = Pat<P>::idx(t, j);
    float sgn = (__popc(i & (i >> 1)) & 1) ? -1.0f : 1.0f;
    float cs = cR[j] * sgn, sn = cI[j] * sgn;
    float r = re[j], q = im[j];
    re[j] = r * cs - q * sn;
    im[j] = r * sn + q * cs;
  }
}

// NOTE: 2nd launch_bounds arg behaves as min BLOCKS per CU on this toolchain
// (R6 evidence: (512,4) -> 4*512*64 = 131072 = full VGPR file -> 64-VGPR cap,
// massive scratch spill, 62 MB FETCH/dispatch). (512,2) -> cap 128.
__global__ __launch_bounds__(NT, 2) void qc_kernel(
    const float* __restrict__ xin,
    const float* __restrict__ thin,
    const float* __restrict__ bin,
    float* __restrict__ out) {
  __shared__ float sRe[NSLOT];
  __shared__ float sIm[NSLOT];
  __shared__ float gCA[65], gSA[65];     // cos/sin(a/2), index l*13+q
  __shared__ float gBbit[65];            // b by [l*13 + bitpos], bitpos p = 12-q
  __shared__ float eBr[65], eBi[65];     // cos(b), sin(b) by [l*13 + bitpos]
  __shared__ float wX[13], wA[13];       // -2x, -2a by bitpos
  __shared__ float cons[8];              // 0:sumX 1:sumA 2:sumA2 3..7:-0.5*sum b_l
  __shared__ float red[NT / 64];

  const int t = threadIdx.x;
  const int b = blockIdx.x;

  if (t < NQ) {
    float xq = xin[b * NQ + t];
    float aq = PI_F - xq;
    wX[12 - t] = -2.0f * xq;
    wA[12 - t] = -2.0f * aq;
  }
  if (t < 65) {
    float av = thin[2 * t];
    float bv = thin[2 * t + 1];
    gCA[t] = cosf(0.5f * av);
    gSA[t] = sinf(0.5f * av);
    int l = t / NQ, q = t % NQ;
    int s = l * NQ + (12 - q);
    gBbit[s] = bv;
    eBr[s] = cosf(bv);
    eBi[s] = sinf(bv);
  }
  __syncthreads();
  if (t == 0) {
    float X = 0.f, A = 0.f, A2 = 0.f;
    for (int p = 0; p < NQ; p++) {
      float xq = -0.5f * wX[p], aq = -0.5f * wA[p];
      X += xq; A += aq; A2 += aq * aq;
    }
    cons[0] = X; cons[1] = A; cons[2] = A2;
    for (int l = 0; l < 5; l++) {
      float s = 0.f;
      for (int p = 0; p < NQ; p++) s += gBbit[l * NQ + p];
      cons[3 + l] = -0.5f * s;
    }
  }
  __syncthreads();

  float re[NAMP], im[NAMP];

  // P0 (pat0): init psi = exp(i*phi); FWHT bits 0-3
  featureDiag<0, true>(re, im, wX, wA, cons, t);
  fwht_all4(re, im);
  storeAmps<0>(sRe, sIm, t, re, im);
  __syncthreads();

  // P1 (pat1): FWHT bits 4-7
  loadAmps<1>(sRe, sIm, t, re, im);
  fwht_all4(re, im);
  storeAmps<1>(sRe, sIm, t, re, im);
  __syncthreads();

  // P2 (pat2): FWHT bits 8-11
  loadAmps<2>(sRe, sIm, t, re, im);
  fwht_all4(re, im);
  storeAmps<2>(sRe, sIm, t, re, im);
  __syncthreads();

  // P3 (pat3): FWHT bit 12; second feature diag; L0 gates on i-bits {0,1,2,12}
  loadAmps<3>(sRe, sIm, t, re, im);
  fwht_bit<3>(re, im);
  featureDiag<3, false>(re, im, wX, wA, cons, t);
  ry4<3>(re, im, gCA, gSA, 0);
  storeAmps<3>(sRe, sIm, t, re, im);
  __syncthreads();

  float acc = 0.0f;
  // layer loop: transitions at patterns alternating 6 (bit 11) and 3 (bit 12)
  #pragma unroll 1
  for (int l = 0; l < 5; l++) {
    // mid pass 1 (pat4): gates on i-bits {3,4,5,6}
    loadAmps<4>(sRe, sIm, t, re, im);
    ry4<4>(re, im, gCA, gSA, l);
    storeAmps<4>(sRe, sIm, t, re, im);
    __syncthreads();
    // mid pass 2 (pat5): gates on i-bits {7,8,9,10}
    loadAmps<5>(sRe, sIm, t, re, im);
    ry4<5>(re, im, gCA, gSA, l);
    storeAmps<5>(sRe, sIm, t, re, im);
    __syncthreads();
    // transition pass: finish layer l (leftover bit), diag l, start layer l+1
    if (l == 4) {
      // P18 (pat6): L4 on i-bit 11 (q=1) + readout
      loadAmps<6>(sRe, sIm, t, re, im);
      ryOn<6, 3>(re, im, gCA, gSA, 4);
      #pragma unroll
      for (int j = 0; j < NAMP; j++) {
        int i = Pat<6>::idx(t, j);
        float p2 = re[j] * re[j] + im[j] * im[j];
        acc += (__popc(i) & 1) ? -p2 : p2;
      }
    } else if ((l & 1) == 0) {
      // pat6: L_l on i-bit 11, diag l, L_{l+1} on {0,1,2,11}
      loadAmps<6>(sRe, sIm, t, re, im);
      ryOn<6, 3>(re, im, gCA, gSA, l);
      applyDiag<6>(re, im, gBbit + l * NQ, eBr + l * NQ, eBi + l * NQ, cons[3 + l], t);
      ry4<6>(re, im, gCA, gSA, l + 1);
      storeAmps<6>(sRe, sIm, t, re, im);
      __syncthreads();
    } else {
      // pat3: L_l on i-bit 12, diag l, L_{l+1} on {0,1,2,12}
      loadAmps<3>(sRe, sIm, t, re, im);
      ryOn<3, 3>(re, im, gCA, gSA, l);
      applyDiag<3>(re, im, gBbit + l * NQ, eBr + l * NQ, eBi + l * NQ, cons[3 + l], t);
      ry4<3>(re, im, gCA, gSA, l + 1);
      storeAmps<3>(sRe, sIm, t, re, im);
      __syncthreads();
    }
  }

  // block reduction (raw scale 2^26)
  #pragma unroll
  for (int off = 32; off > 0; off >>= 1) acc += __shfl_down(acc, off, 64);
  if ((t & 63) == 0) red[t >> 6] = acc;
  __syncthreads();
  if (t == 0) {
    float total = 0.f;
    #pragma unroll
    for (int w = 0; w < NT / 64; w++) total += red[w];
    float logit = total * (1.0f / 67108864.0f) + bin[0];
    out[b * 2 + 0] = -logit;
    out[b * 2 + 1] = logit;
  }
}

extern "C" void kernel_launch(void* const* d_in, const int* in_sizes, int n_in,
                              void* d_out, int out_size, void* d_ws, size_t ws_size,
                              hipStream_t stream) {
  const float* x  = (const float*)d_in[0];
  const float* th = (const float*)d_in[1];
  const float* bi = (const float*)d_in[2];
  float* out = (float*)d_out;
  int B = in_sizes[0] / NQ;   // 512
  qc_kernel<<<B, NT, 0, stream>>>(x, th, bi, out);
}

// Round 8
// 106.114 us; speedup vs baseline: 1.2720x; 1.1024x over previous
//
#include <hip/hip_runtime.h>

#define NQ   13
#define DIM  8192
#define PI_F 3.14159265358979323846f
#define NT   256     // threads per block (4 waves); 2 blocks/CU (LDS-bound)
#define NAMP 32      // amplitudes per thread (5-bit register window)

// LDS slot with +1 float pad per 32 -> <=2-way bank aliasing (free, m136)
__device__ __forceinline__ int lslot(int i) { return i + (i >> 5); }
#define NSLOT (DIM + (DIM >> 5))   // 8448 floats per component array

// range-reduced fast sincos
__device__ __forceinline__ void rsincos(float x, float* s, float* c) {
  const float INV2PI = 0.15915494309189535f;
  const float TWOPI  = 6.283185307179586f;
  float r = x * INV2PI;
  r -= rintf(r);
  float ang = r * TWOPI;
  *s = __sinf(ang);
  *c = __cosf(ang);
}

// ---- float2 componentwise helpers: same real coefficient on .x/.y ->
// LLVM SLP packs these into v_pk_mul_f32 / v_pk_fma_f32 (2 fp32/inst)
__device__ __forceinline__ float2 f2mul(float2 a, float s) {
  return make_float2(a.x * s, a.y * s);
}
__device__ __forceinline__ float2 f2fma(float s, float2 a, float2 b) {
  return make_float2(fmaf(s, a.x, b.x), fmaf(s, a.y, b.y));
}
__device__ __forceinline__ float2 f2add(float2 a, float2 b) {
  return make_float2(a.x + b.x, a.y + b.y);
}
__device__ __forceinline__ float2 f2sub(float2 a, float2 b) {
  return make_float2(a.x - b.x, a.y - b.y);
}
// amp *= (cs + i*sn)
__device__ __forceinline__ float2 cphase(float2 v, float cs, float sn) {
  return make_float2(fmaf(cs, v.x, -sn * v.y), fmaf(cs, v.y, sn * v.x));
}
// complex multiply
__device__ __forceinline__ float2 cmul(float2 a, float2 b) {
  return make_float2(fmaf(a.x, b.x, -a.y * b.y), fmaf(a.x, b.y, a.y * b.x));
}

// ---------------------------------------------------------------------------
// Pass patterns (R5-verified): each thread owns 32 amps over 5 bit positions.
//  PAT0: i = (t<<5) | j
//  PAT1: i = ((t>>5)<<10) | (j<<5) | (t&31)
//  PAT2: i = ((j>>2)<<10) | (t<<2) | (j&3)
// ---------------------------------------------------------------------------
template<int PAT>
__device__ __forceinline__ int ampIndex(int t, int j) {
  if constexpr (PAT == 0) return (t << 5) | j;
  else if constexpr (PAT == 1) return ((t >> 5) << 10) | (j << 5) | (t & 31);
  else return ((j >> 2) << 10) | (t << 2) | (j & 3);
}

// s[j] = bias + sum over set bits p of i(t,j) of w[p]  (w indexed by bit pos)
template<int PAT>
__device__ __forceinline__ void buildTree(const float* __restrict__ w, float bias,
                                          int t, float* s) {
  float base = bias;
  if constexpr (PAT == 0) {
    #pragma unroll
    for (int k = 0; k < 8; k++) base += ((t >> k) & 1) ? w[5 + k] : 0.0f;
  } else if constexpr (PAT == 1) {
    #pragma unroll
    for (int k = 0; k < 5; k++) base += ((t >> k) & 1) ? w[k] : 0.0f;
    #pragma unroll
    for (int k = 0; k < 3; k++) base += ((t >> (5 + k)) & 1) ? w[10 + k] : 0.0f;
  } else {
    #pragma unroll
    for (int k = 0; k < 8; k++) base += ((t >> k) & 1) ? w[2 + k] : 0.0f;
  }
  constexpr int P[5] = { (PAT == 1) ? 5 : 0,
                         (PAT == 1) ? 6 : 1,
                         (PAT == 0) ? 2 : ((PAT == 1) ? 7 : 10),
                         (PAT == 0) ? 3 : ((PAT == 1) ? 8 : 11),
                         (PAT == 0) ? 4 : ((PAT == 1) ? 9 : 12) };
  s[0] = base;
  #pragma unroll
  for (int k = 0; k < 5; k++) {
    float wp = w[P[k]];
    #pragma unroll
    for (int m = 0; m < (1 << k); m++) s[m | (1 << k)] = s[m] + wp;
  }
}

template<int PAT>
__device__ __forceinline__ void loadAmps(const float* __restrict__ sRe,
                                         const float* __restrict__ sIm,
                                         int t, float2* amp) {
  #pragma unroll
  for (int j = 0; j < NAMP; j++) {
    int a = lslot(ampIndex<PAT>(t, j));
    amp[j] = make_float2(sRe[a], sIm[a]);
  }
}

template<int PAT>
__device__ __forceinline__ void storeAmps(float* __restrict__ sRe,
                                          float* __restrict__ sIm,
                                          int t, const float2* amp) {
  #pragma unroll
  for (int j = 0; j < NAMP; j++) {
    int a = lslot(ampIndex<PAT>(t, j));
    sRe[a] = amp[j].x; sIm[a] = amp[j].y;
  }
}

template<int KB>
__device__ __forceinline__ void fwht_bit(float2* amp) {
  #pragma unroll
  for (int j = 0; j < NAMP; j++) if (!(j & (1 << KB))) {
    int j1 = j | (1 << KB);
    float2 a0 = amp[j], a1 = amp[j1];
    amp[j]  = f2add(a0, a1);
    amp[j1] = f2sub(a0, a1);
  }
}
__device__ __forceinline__ void fwht_all5(float2* amp) {
  fwht_bit<0>(amp); fwht_bit<1>(amp); fwht_bit<2>(amp);
  fwht_bit<3>(amp); fwht_bit<4>(amp);
}

// Ry on register bit KB (real coefficients -> fully packable)
template<int KB>
__device__ __forceinline__ void applyRy(float2* amp, float ca, float sa) {
  #pragma unroll
  for (int j = 0; j < NAMP; j++) if (!(j & (1 << KB))) {
    int j1 = j | (1 << KB);
    float2 a0 = amp[j], a1 = amp[j1];
    amp[j]  = f2fma(-sa, a1, f2mul(a0, ca));
    amp[j1] = f2fma( sa, a0, f2mul(a1, ca));
  }
}

// psi *= exp(i*phi(i)), phi = u + 0.5*(v^2 - A2); INIT writes unit phase
template<int PAT, bool INIT>
__device__ __forceinline__ void featureDiag(float2* amp,
                                            const float* __restrict__ wX,
                                            const float* __restrict__ wA,
                                            const float* __restrict__ cons, int t) {
  float u[NAMP], v[NAMP];
  buildTree<PAT>(wX, cons[0], t, u);
  buildTree<PAT>(wA, cons[1], t, v);
  float A2 = cons[2];
  #pragma unroll
  for (int j = 0; j < NAMP; j++) {
    float phi = u[j] + 0.5f * (v[j] * v[j] - A2);
    float sn, cs; rsincos(phi, &sn, &cs);
    if constexpr (INIT) amp[j] = make_float2(cs, sn);
    else                amp[j] = cphase(amp[j], cs, sn);
  }
}

// psi *= ENT(i) * exp(i*rho(i)) on PAT0; rho linear in bits -> product tree:
// 1 rsincos + 31 cmul instead of 32 rsincos (R7-verified math)
__device__ __forceinline__ void applyDiagPT(float2* amp,
                                            const float* __restrict__ wb,  // b by bitpos (layer slice)
                                            const float* __restrict__ eR,  // cos(b) by bitpos
                                            const float* __restrict__ eI,  // sin(b) by bitpos
                                            float bias, int t) {
  float base = bias;
  #pragma unroll
  for (int k = 0; k < 8; k++) base += ((t >> k) & 1) ? wb[5 + k] : 0.0f;
  float2 c[NAMP];
  { float sn, cs; rsincos(base, &sn, &cs); c[0] = make_float2(cs, sn); }
  #pragma unroll
  for (int k = 0; k < 5; k++) {
    float2 e = make_float2(eR[k], eI[k]);   // PAT0 window bit k = i-bit k
    #pragma unroll
    for (int m = 0; m < (1 << k); m++) c[m | (1 << k)] = cmul(c[m], e);
  }
  #pragma unroll
  for (int j = 0; j < NAMP; j++) {
    int i = ampIndex<0>(t, j);
    float sgn = (__popc(i & (i >> 1)) & 1) ? -1.0f : 1.0f;
    amp[j] = cphase(amp[j], c[j].x * sgn, c[j].y * sgn);
  }
}

// 2nd launch_bounds arg acts as min BLOCKS/CU here (R6 evidence: (512,4)
// capped VGPR at 64 -> spill). (256,2) -> 256-VGPR cap, LDS limits to 2/CU.
__global__ __launch_bounds__(NT, 2) void qc_kernel(
    const float* __restrict__ xin,
    const float* __restrict__ thin,
    const float* __restrict__ bin,
    float* __restrict__ out) {
  __shared__ float sRe[NSLOT];
  __shared__ float sIm[NSLOT];
  __shared__ float gCA[65], gSA[65];   // cos/sin(a/2) per gate l*13+q
  __shared__ float gBbit[65];          // b by [l*13 + bitpos], bitpos = 12-q
  __shared__ float eBr[65], eBi[65];   // cos(b), sin(b) by [l*13 + bitpos]
  __shared__ float wX[13], wA[13];     // -2x, -2a by bitpos
  __shared__ float cons[8];            // 0:X 1:A 2:A2 3..7:-0.5*sum b_l
  __shared__ float red[NT / 64];

  const int t = threadIdx.x;
  const int b = blockIdx.x;

  if (t < NQ) {
    float xq = xin[b * NQ + t];
    float aq = PI_F - xq;
    wX[12 - t] = -2.0f * xq;
    wA[12 - t] = -2.0f * aq;
  }
  if (t < 65) {
    float av = thin[2 * t];
    float bv = thin[2 * t + 1];
    gCA[t] = cosf(0.5f * av);
    gSA[t] = sinf(0.5f * av);
    int l = t / NQ, q = t % NQ;
    int s = l * NQ + (12 - q);
    gBbit[s] = bv;
    eBr[s] = cosf(bv);
    eBi[s] = sinf(bv);
  }
  __syncthreads();
  if (t == 0) {
    float X = 0.f, A = 0.f, A2 = 0.f;
    for (int p = 0; p < NQ; p++) {
      float xq = -0.5f * wX[p], aq = -0.5f * wA[p];
      X += xq; A += aq; A2 += aq * aq;
    }
    cons[0] = X; cons[1] = A; cons[2] = A2;
    for (int l = 0; l < 5; l++) {
      float s = 0.f;
      for (int p = 0; p < NQ; p++) s += gBbit[l * NQ + p];
      cons[3 + l] = -0.5f * s;
    }
  }
  __syncthreads();

  float2 amp[NAMP];

  // ---- Pass 0 (PAT0): psi = exp(i*phi); FWHT bits 0..4
  featureDiag<0, true>(amp, wX, wA, cons, t);
  fwht_all5(amp);
  storeAmps<0>(sRe, sIm, t, amp);
  __syncthreads();

  // ---- Pass 1 (PAT1): FWHT bits 5..9
  loadAmps<1>(sRe, sIm, t, amp);
  fwht_all5(amp);
  storeAmps<1>(sRe, sIm, t, amp);
  __syncthreads();

  // ---- Pass 2 (PAT2): FWHT bits 10..12; second feature-map diagonal
  loadAmps<2>(sRe, sIm, t, amp);
  fwht_bit<2>(amp); fwht_bit<3>(amp); fwht_bit<4>(amp);
  featureDiag<2, false>(amp, wX, wA, cons, t);
  storeAmps<2>(sRe, sIm, t, amp);
  __syncthreads();

  // ---- Variational layers: Ry only; Rz(b_{l-1})+ENT fused diagonal at pass A
  float acc = 0.0f;
  for (int l = 0; l < 5; l++) {
    const int g = l * NQ;
    // pass A (PAT0): bits 0..4 (qubits 12..8)
    loadAmps<0>(sRe, sIm, t, amp);
    if (l > 0) applyDiagPT(amp, gBbit + (l - 1) * NQ, eBr + (l - 1) * NQ,
                           eBi + (l - 1) * NQ, cons[3 + (l - 1)], t);
    applyRy<0>(amp, gCA[g + 12], gSA[g + 12]);
    applyRy<1>(amp, gCA[g + 11], gSA[g + 11]);
    applyRy<2>(amp, gCA[g + 10], gSA[g + 10]);
    applyRy<3>(amp, gCA[g + 9],  gSA[g + 9]);
    applyRy<4>(amp, gCA[g + 8],  gSA[g + 8]);
    storeAmps<0>(sRe, sIm, t, amp);
    __syncthreads();
    // pass B (PAT1): bits 5..9 (qubits 7..3)
    loadAmps<1>(sRe, sIm, t, amp);
    applyRy<0>(amp, gCA[g + 7], gSA[g + 7]);
    applyRy<1>(amp, gCA[g + 6], gSA[g + 6]);
    applyRy<2>(amp, gCA[g + 5], gSA[g + 5]);
    applyRy<3>(amp, gCA[g + 4], gSA[g + 4]);
    applyRy<4>(amp, gCA[g + 3], gSA[g + 3]);
    storeAmps<1>(sRe, sIm, t, amp);
    __syncthreads();
    // pass C (PAT2): bits 10..12 (qubits 2..0); last layer fuses readout
    loadAmps<2>(sRe, sIm, t, amp);
    applyRy<2>(amp, gCA[g + 2], gSA[g + 2]);
    applyRy<3>(amp, gCA[g + 1], gSA[g + 1]);
    applyRy<4>(amp, gCA[g + 0], gSA[g + 0]);
    if (l < 4) {
      storeAmps<2>(sRe, sIm, t, amp);
      __syncthreads();
    } else {
      // trailing Rz is diagonal -> invisible in |psi|^2; readout here
      #pragma unroll
      for (int j = 0; j < NAMP; j++) {
        int i = ampIndex<2>(t, j);
        float p2 = fmaf(amp[j].x, amp[j].x, amp[j].y * amp[j].y);
        acc += (__popc(i) & 1) ? -p2 : p2;
      }
    }
  }

  // block reduction (raw scale 2^26)
  #pragma unroll
  for (int off = 32; off > 0; off >>= 1) acc += __shfl_down(acc, off, 64);
  if ((t & 63) == 0) red[t >> 6] = acc;
  __syncthreads();
  if (t == 0) {
    float total = red[0] + red[1] + red[2] + red[3];
    float logit = total * (1.0f / 67108864.0f) + bin[0];
    out[b * 2 + 0] = -logit;
    out[b * 2 + 1] = logit;
  }
}

extern "C" void kernel_launch(void* const* d_in, const int* in_sizes, int n_in,
                              void* d_out, int out_size, void* d_ws, size_t ws_size,
                              hipStream_t stream) {
  const float* x  = (const float*)d_in[0];
  const float* th = (const float*)d_in[1];
  const float* bi = (const float*)d_in[2];
  float* out = (float*)d_out;
  int B = in_sizes[0] / NQ;   // 512
  qc_kernel<<<B, NT, 0, stream>>>(x, th, bi, out);
}

// Round 9
// 97.991 us; speedup vs baseline: 1.3774x; 1.0829x over previous
//
#include <hip/hip_runtime.h>

#define NQ   13
#define DIM  8192
#define PI_F 3.14159265358979323846f
#define NT   256     // threads per block (4 waves); 2 blocks/CU (LDS-bound)
#define NAMP 32      // amplitudes per thread (5-bit register window)

// LDS slot with +1 float2 pad per 32 -> b64 accesses hit 4 words/bank
// (the 512B/4cyc data-bound minimum) for all three patterns
__device__ __forceinline__ int lslot(int i) { return i + (i >> 5); }
#define NSLOT (DIM + (DIM >> 5))   // 8448 float2 slots = 67.6 KB

// range-reduced fast sincos
__device__ __forceinline__ void rsincos(float x, float* s, float* c) {
  const float INV2PI = 0.15915494309189535f;
  const float TWOPI  = 6.283185307179586f;
  float r = x * INV2PI;
  r -= rintf(r);
  float ang = r * TWOPI;
  *s = __sinf(ang);
  *c = __cosf(ang);
}

// ---- float2 componentwise helpers (same real coefficient on .x/.y -> v_pk_*)
__device__ __forceinline__ float2 f2mul(float2 a, float s) {
  return make_float2(a.x * s, a.y * s);
}
__device__ __forceinline__ float2 f2fma(float s, float2 a, float2 b) {
  return make_float2(fmaf(s, a.x, b.x), fmaf(s, a.y, b.y));
}
__device__ __forceinline__ float2 f2add(float2 a, float2 b) {
  return make_float2(a.x + b.x, a.y + b.y);
}
__device__ __forceinline__ float2 f2sub(float2 a, float2 b) {
  return make_float2(a.x - b.x, a.y - b.y);
}
// amp *= (cs + i*sn)
__device__ __forceinline__ float2 cphase(float2 v, float cs, float sn) {
  return make_float2(fmaf(cs, v.x, -sn * v.y), fmaf(cs, v.y, sn * v.x));
}
// complex multiply
__device__ __forceinline__ float2 cmul(float2 a, float2 b) {
  return make_float2(fmaf(a.x, b.x, -a.y * b.y), fmaf(a.x, b.y, a.y * b.x));
}

// ---------------------------------------------------------------------------
// Pass patterns (R5-verified): each thread owns 32 amps over 5 bit positions.
//  PAT0: i = (t<<5) | j
//  PAT1: i = ((t>>5)<<10) | (j<<5) | (t&31)
//  PAT2: i = ((j>>2)<<10) | (t<<2) | (j&3)
// ---------------------------------------------------------------------------
template<int PAT>
__device__ __forceinline__ int ampIndex(int t, int j) {
  if constexpr (PAT == 0) return (t << 5) | j;
  else if constexpr (PAT == 1) return ((t >> 5) << 10) | (j << 5) | (t & 31);
  else return ((j >> 2) << 10) | (t << 2) | (j & 3);
}

// s[j] = bias + sum over set bits p of i(t,j) of w[p]  (w indexed by bit pos)
template<int PAT>
__device__ __forceinline__ void buildTree(const float* __restrict__ w, float bias,
                                          int t, float* s) {
  float base = bias;
  if constexpr (PAT == 0) {
    #pragma unroll
    for (int k = 0; k < 8; k++) base += ((t >> k) & 1) ? w[5 + k] : 0.0f;
  } else if constexpr (PAT == 1) {
    #pragma unroll
    for (int k = 0; k < 5; k++) base += ((t >> k) & 1) ? w[k] : 0.0f;
    #pragma unroll
    for (int k = 0; k < 3; k++) base += ((t >> (5 + k)) & 1) ? w[10 + k] : 0.0f;
  } else {
    #pragma unroll
    for (int k = 0; k < 8; k++) base += ((t >> k) & 1) ? w[2 + k] : 0.0f;
  }
  constexpr int P[5] = { (PAT == 1) ? 5 : 0,
                         (PAT == 1) ? 6 : 1,
                         (PAT == 0) ? 2 : ((PAT == 1) ? 7 : 10),
                         (PAT == 0) ? 3 : ((PAT == 1) ? 8 : 11),
                         (PAT == 0) ? 4 : ((PAT == 1) ? 9 : 12) };
  s[0] = base;
  #pragma unroll
  for (int k = 0; k < 5; k++) {
    float wp = w[P[k]];
    #pragma unroll
    for (int m = 0; m < (1 << k); m++) s[m | (1 << k)] = s[m] + wp;
  }
}

template<int PAT>
__device__ __forceinline__ void loadAmps(const float2* __restrict__ sAmp,
                                         int t, float2* amp) {
  #pragma unroll
  for (int j = 0; j < NAMP; j++) {
    amp[j] = sAmp[lslot(ampIndex<PAT>(t, j))];   // ds_read_b64
  }
}

template<int PAT>
__device__ __forceinline__ void storeAmps(float2* __restrict__ sAmp,
                                          int t, const float2* amp) {
  #pragma unroll
  for (int j = 0; j < NAMP; j++) {
    sAmp[lslot(ampIndex<PAT>(t, j))] = amp[j];   // ds_write_b64
  }
}

template<int KB>
__device__ __forceinline__ void fwht_bit(float2* amp) {
  #pragma unroll
  for (int j = 0; j < NAMP; j++) if (!(j & (1 << KB))) {
    int j1 = j | (1 << KB);
    float2 a0 = amp[j], a1 = amp[j1];
    amp[j]  = f2add(a0, a1);
    amp[j1] = f2sub(a0, a1);
  }
}
__device__ __forceinline__ void fwht_all5(float2* amp) {
  fwht_bit<0>(amp); fwht_bit<1>(amp); fwht_bit<2>(amp);
  fwht_bit<3>(amp); fwht_bit<4>(amp);
}

// Ry on register bit KB (real coefficients -> fully packable)
template<int KB>
__device__ __forceinline__ void applyRy(float2* amp, float ca, float sa) {
  #pragma unroll
  for (int j = 0; j < NAMP; j++) if (!(j & (1 << KB))) {
    int j1 = j | (1 << KB);
    float2 a0 = amp[j], a1 = amp[j1];
    amp[j]  = f2fma(-sa, a1, f2mul(a0, ca));
    amp[j1] = f2fma( sa, a0, f2mul(a1, ca));
  }
}

// psi *= exp(i*phi(i)), phi = u + 0.5*(v^2 - A2); INIT writes unit phase
template<int PAT, bool INIT>
__device__ __forceinline__ void featureDiag(float2* amp,
                                            const float* __restrict__ wX,
                                            const float* __restrict__ wA,
                                            const float* __restrict__ cons, int t) {
  float u[NAMP], v[NAMP];
  buildTree<PAT>(wX, cons[0], t, u);
  buildTree<PAT>(wA, cons[1], t, v);
  float A2 = cons[2];
  #pragma unroll
  for (int j = 0; j < NAMP; j++) {
    float phi = u[j] + 0.5f * (v[j] * v[j] - A2);
    float sn, cs; rsincos(phi, &sn, &cs);
    if constexpr (INIT) amp[j] = make_float2(cs, sn);
    else                amp[j] = cphase(amp[j], cs, sn);
  }
}

// psi *= ENT(i) * exp(i*rho(i)) on PAT0; rho linear in bits -> product tree:
// 1 rsincos + 31 cmul instead of 32 rsincos (R7-verified math)
__device__ __forceinline__ void applyDiagPT(float2* amp,
                                            const float* __restrict__ wb,  // b by bitpos (layer slice)
                                            const float* __restrict__ eR,  // cos(b) by bitpos
                                            const float* __restrict__ eI,  // sin(b) by bitpos
                                            float bias, int t) {
  float base = bias;
  #pragma unroll
  for (int k = 0; k < 8; k++) base += ((t >> k) & 1) ? wb[5 + k] : 0.0f;
  float2 c[NAMP];
  { float sn, cs; rsincos(base, &sn, &cs); c[0] = make_float2(cs, sn); }
  #pragma unroll
  for (int k = 0; k < 5; k++) {
    float2 e = make_float2(eR[k], eI[k]);   // PAT0 window bit k = i-bit k
    #pragma unroll
    for (int m = 0; m < (1 << k); m++) c[m | (1 << k)] = cmul(c[m], e);
  }
  #pragma unroll
  for (int j = 0; j < NAMP; j++) {
    int i = ampIndex<0>(t, j);
    float sgn = (__popc(i & (i >> 1)) & 1) ? -1.0f : 1.0f;
    amp[j] = cphase(amp[j], c[j].x * sgn, c[j].y * sgn);
  }
}

// 2nd launch_bounds arg acts as min BLOCKS/CU here (R6 evidence)
__global__ __launch_bounds__(NT, 2) void qc_kernel(
    const float* __restrict__ xin,
    const float* __restrict__ thin,
    const float* __restrict__ bin,
    float* __restrict__ out) {
  __shared__ float2 sAmp[NSLOT];       // interleaved re/im: b64 per amp
  __shared__ float gCA[65], gSA[65];   // cos/sin(a/2) per gate l*13+q
  __shared__ float gBbit[65];          // b by [l*13 + bitpos], bitpos = 12-q
  __shared__ float eBr[65], eBi[65];   // cos(b), sin(b) by [l*13 + bitpos]
  __shared__ float wX[13], wA[13];     // -2x, -2a by bitpos
  __shared__ float cons[8];            // 0:X 1:A 2:A2 3..7:-0.5*sum b_l
  __shared__ float red[NT / 64];

  const int t = threadIdx.x;
  const int b = blockIdx.x;

  if (t < NQ) {
    float xq = xin[b * NQ + t];
    float aq = PI_F - xq;
    wX[12 - t] = -2.0f * xq;
    wA[12 - t] = -2.0f * aq;
  }
  if (t < 65) {
    float av = thin[2 * t];
    float bv = thin[2 * t + 1];
    gCA[t] = cosf(0.5f * av);
    gSA[t] = sinf(0.5f * av);
    int l = t / NQ, q = t % NQ;
    int s = l * NQ + (12 - q);
    gBbit[s] = bv;
    eBr[s] = cosf(bv);
    eBi[s] = sinf(bv);
  }
  __syncthreads();
  if (t == 0) {
    float X = 0.f, A = 0.f, A2 = 0.f;
    for (int p = 0; p < NQ; p++) {
      float xq = -0.5f * wX[p], aq = -0.5f * wA[p];
      X += xq; A += aq; A2 += aq * aq;
    }
    cons[0] = X; cons[1] = A; cons[2] = A2;
    for (int l = 0; l < 5; l++) {
      float s = 0.f;
      for (int p = 0; p < NQ; p++) s += gBbit[l * NQ + p];
      cons[3 + l] = -0.5f * s;
    }
  }
  __syncthreads();

  float2 amp[NAMP];

  // ---- Pass 0 (PAT0): psi = exp(i*phi); FWHT bits 0..4
  featureDiag<0, true>(amp, wX, wA, cons, t);
  fwht_all5(amp);
  storeAmps<0>(sAmp, t, amp);
  __syncthreads();

  // ---- Pass 1 (PAT1): FWHT bits 5..9
  loadAmps<1>(sAmp, t, amp);
  fwht_all5(amp);
  storeAmps<1>(sAmp, t, amp);
  __syncthreads();

  // ---- Pass 2 (PAT2): FWHT bits 10..12; second feature-map diagonal
  loadAmps<2>(sAmp, t, amp);
  fwht_bit<2>(amp); fwht_bit<3>(amp); fwht_bit<4>(amp);
  featureDiag<2, false>(amp, wX, wA, cons, t);
  storeAmps<2>(sAmp, t, amp);
  __syncthreads();

  // ---- Variational layers: Ry only; Rz(b_{l-1})+ENT fused diagonal at pass A
  float acc = 0.0f;
  for (int l = 0; l < 5; l++) {
    const int g = l * NQ;
    // pass A (PAT0): bits 0..4 (qubits 12..8)
    loadAmps<0>(sAmp, t, amp);
    if (l > 0) applyDiagPT(amp, gBbit + (l - 1) * NQ, eBr + (l - 1) * NQ,
                           eBi + (l - 1) * NQ, cons[3 + (l - 1)], t);
    applyRy<0>(amp, gCA[g + 12], gSA[g + 12]);
    applyRy<1>(amp, gCA[g + 11], gSA[g + 11]);
    applyRy<2>(amp, gCA[g + 10], gSA[g + 10]);
    applyRy<3>(amp, gCA[g + 9],  gSA[g + 9]);
    applyRy<4>(amp, gCA[g + 8],  gSA[g + 8]);
    storeAmps<0>(sAmp, t, amp);
    __syncthreads();
    // pass B (PAT1): bits 5..9 (qubits 7..3)
    loadAmps<1>(sAmp, t, amp);
    applyRy<0>(amp, gCA[g + 7], gSA[g + 7]);
    applyRy<1>(amp, gCA[g + 6], gSA[g + 6]);
    applyRy<2>(amp, gCA[g + 5], gSA[g + 5]);
    applyRy<3>(amp, gCA[g + 4], gSA[g + 4]);
    applyRy<4>(amp, gCA[g + 3], gSA[g + 3]);
    storeAmps<1>(sAmp, t, amp);
    __syncthreads();
    // pass C (PAT2): bits 10..12 (qubits 2..0); last layer fuses readout
    loadAmps<2>(sAmp, t, amp);
    applyRy<2>(amp, gCA[g + 2], gSA[g + 2]);
    applyRy<3>(amp, gCA[g + 1], gSA[g + 1]);
    applyRy<4>(amp, gCA[g + 0], gSA[g + 0]);
    if (l < 4) {
      storeAmps<2>(sAmp, t, amp);
      __syncthreads();
    } else {
      // trailing Rz is diagonal -> invisible in |psi|^2; readout here
      #pragma unroll
      for (int j = 0; j < NAMP; j++) {
        int i = ampIndex<2>(t, j);
        float p2 = fmaf(amp[j].x, amp[j].x, amp[j].y * amp[j].y);
        acc += (__popc(i) & 1) ? -p2 : p2;
      }
    }
  }

  // block reduction (raw scale 2^26)
  #pragma unroll
  for (int off = 32; off > 0; off >>= 1) acc += __shfl_down(acc, off, 64);
  if ((t & 63) == 0) red[t >> 6] = acc;
  __syncthreads();
  if (t == 0) {
    float total = red[0] + red[1] + red[2] + red[3];
    float logit = total * (1.0f / 67108864.0f) + bin[0];
    out[b * 2 + 0] = -logit;
    out[b * 2 + 1] = logit;
  }
}

extern "C" void kernel_launch(void* const* d_in, const int* in_sizes, int n_in,
                              void* d_out, int out_size, void* d_ws, size_t ws_size,
                              hipStream_t stream) {
  const float* x  = (const float*)d_in[0];
  const float* th = (const float*)d_in[1];
  const float* bi = (const float*)d_in[2];
  float* out = (float*)d_out;
  int B = in_sizes[0] / NQ;   // 512
  qc_kernel<<<B, NT, 0, stream>>>(x, th, bi, out);
}

// Round 10
// 95.773 us; speedup vs baseline: 1.4093x; 1.0232x over previous
//
#include <hip/hip_runtime.h>

#define NQ   13
#define DIM  8192
#define PI_F 3.14159265358979323846f
#define NT   256     // threads per block (4 waves); 2 blocks/CU (LDS-bound)
#define NAMP 32      // amplitudes per thread (5-bit register window)

// LDS slot with +1 float2 pad per 32 -> b64 accesses at the 4-words/bank-pair
// data floor for all three patterns (verified per-pattern)
__device__ __forceinline__ int lslot(int i) { return i + (i >> 5); }
#define NSLOT (DIM + (DIM >> 5))   // 8448 float2 slots = 67.6 KB

// range-reduced fast sincos
__device__ __forceinline__ void rsincos(float x, float* s, float* c) {
  const float INV2PI = 0.15915494309189535f;
  const float TWOPI  = 6.283185307179586f;
  float r = x * INV2PI;
  r -= rintf(r);
  float ang = r * TWOPI;
  *s = __sinf(ang);
  *c = __cosf(ang);
}

// wave-local "barrier": PAT0<->PAT1 quarter-states are wave-private (both pin
// i-bits{11,12}=wave id) and same-wave DS ops complete in order -> only a
// compiler memory fence is needed, no inter-wave sync.
__device__ __forceinline__ void waveFence() {
  __builtin_amdgcn_wave_barrier();
  __threadfence_block();
  __builtin_amdgcn_wave_barrier();
}

// ---- float2 componentwise helpers (same real coefficient on .x/.y -> v_pk_*)
__device__ __forceinline__ float2 f2fma(float s, float2 a, float2 b) {
  return make_float2(fmaf(s, a.x, b.x), fmaf(s, a.y, b.y));
}
__device__ __forceinline__ float2 f2add(float2 a, float2 b) {
  return make_float2(a.x + b.x, a.y + b.y);
}
__device__ __forceinline__ float2 f2sub(float2 a, float2 b) {
  return make_float2(a.x - b.x, a.y - b.y);
}
// amp *= (cs + i*sn)
__device__ __forceinline__ float2 cphase(float2 v, float cs, float sn) {
  return make_float2(fmaf(cs, v.x, -sn * v.y), fmaf(cs, v.y, sn * v.x));
}
// complex multiply
__device__ __forceinline__ float2 cmul(float2 a, float2 b) {
  return make_float2(fmaf(a.x, b.x, -a.y * b.y), fmaf(a.x, b.y, a.y * b.x));
}

// ---------------------------------------------------------------------------
// Pass patterns (R5-verified): each thread owns 32 amps over 5 bit positions.
//  PAT0: i = (t<<5) | j                       (pins i bits 11,12 = wave id)
//  PAT1: i = ((t>>5)<<10) | (j<<5) | (t&31)   (pins i bits 11,12 = wave id)
//  PAT2: i = ((j>>2)<<10) | (t<<2) | (j&3)    (pins i bits 8,9  = wave id)
// ---------------------------------------------------------------------------
template<int PAT>
__device__ __forceinline__ int ampIndex(int t, int j) {
  if constexpr (PAT == 0) return (t << 5) | j;
  else if constexpr (PAT == 1) return ((t >> 5) << 10) | (j << 5) | (t & 31);
  else return ((j >> 2) << 10) | (t << 2) | (j & 3);
}

// s[j] = bias + sum over set bits p of i(t,j) of w[p]  (w indexed by bit pos)
template<int PAT>
__device__ __forceinline__ void buildTree(const float* __restrict__ w, float bias,
                                          int t, float* s) {
  float base = bias;
  if constexpr (PAT == 0) {
    #pragma unroll
    for (int k = 0; k < 8; k++) base += ((t >> k) & 1) ? w[5 + k] : 0.0f;
  } else if constexpr (PAT == 1) {
    #pragma unroll
    for (int k = 0; k < 5; k++) base += ((t >> k) & 1) ? w[k] : 0.0f;
    #pragma unroll
    for (int k = 0; k < 3; k++) base += ((t >> (5 + k)) & 1) ? w[10 + k] : 0.0f;
  } else {
    #pragma unroll
    for (int k = 0; k < 8; k++) base += ((t >> k) & 1) ? w[2 + k] : 0.0f;
  }
  constexpr int P[5] = { (PAT == 1) ? 5 : 0,
                         (PAT == 1) ? 6 : 1,
                         (PAT == 0) ? 2 : ((PAT == 1) ? 7 : 10),
                         (PAT == 0) ? 3 : ((PAT == 1) ? 8 : 11),
                         (PAT == 0) ? 4 : ((PAT == 1) ? 9 : 12) };
  s[0] = base;
  #pragma unroll
  for (int k = 0; k < 5; k++) {
    float wp = w[P[k]];
    #pragma unroll
    for (int m = 0; m < (1 << k); m++) s[m | (1 << k)] = s[m] + wp;
  }
}

template<int PAT>
__device__ __forceinline__ void loadAmps(const float2* __restrict__ sAmp,
                                         int t, float2* amp) {
  #pragma unroll
  for (int j = 0; j < NAMP; j++) {
    amp[j] = sAmp[lslot(ampIndex<PAT>(t, j))];   // ds_read_b64
  }
}

template<int PAT>
__device__ __forceinline__ void storeAmps(float2* __restrict__ sAmp,
                                          int t, const float2* amp) {
  #pragma unroll
  for (int j = 0; j < NAMP; j++) {
    sAmp[lslot(ampIndex<PAT>(t, j))] = amp[j];   // ds_write_b64
  }
}

template<int KB>
__device__ __forceinline__ void fwht_bit(float2* amp) {
  #pragma unroll
  for (int j = 0; j < NAMP; j++) if (!(j & (1 << KB))) {
    int j1 = j | (1 << KB);
    float2 a0 = amp[j], a1 = amp[j1];
    amp[j]  = f2add(a0, a1);
    amp[j1] = f2sub(a0, a1);
  }
}
__device__ __forceinline__ void fwht_all5(float2* amp) {
  fwht_bit<0>(amp); fwht_bit<1>(amp); fwht_bit<2>(amp);
  fwht_bit<3>(amp); fwht_bit<4>(amp);
}

// Ry on register bit KB via 3 shears: tau = sa/(1+ca), safe for |theta|<pi.
// a0 -= tau*a1; a1 += sa*a0; a0 -= tau*a1  ==  [ca,-sa; sa,ca]
// 3 pk-fma per pair vs 4 pk-insts for the direct form.
template<int KB>
__device__ __forceinline__ void applyRy(float2* amp, float ta, float sa) {
  #pragma unroll
  for (int j = 0; j < NAMP; j++) if (!(j & (1 << KB))) {
    int j1 = j | (1 << KB);
    amp[j]  = f2fma(-ta, amp[j1], amp[j]);
    amp[j1] = f2fma( sa, amp[j],  amp[j1]);
    amp[j]  = f2fma(-ta, amp[j1], amp[j]);
  }
}

// psi *= exp(i*phi(i)), phi = u + 0.5*(v^2 - A2); INIT writes unit phase
template<int PAT, bool INIT>
__device__ __forceinline__ void featureDiag(float2* amp,
                                            const float* __restrict__ wX,
                                            const float* __restrict__ wA,
                                            const float* __restrict__ cons, int t) {
  float u[NAMP], v[NAMP];
  buildTree<PAT>(wX, cons[0], t, u);
  buildTree<PAT>(wA, cons[1], t, v);
  float A2 = cons[2];
  #pragma unroll
  for (int j = 0; j < NAMP; j++) {
    float phi = u[j] + 0.5f * (v[j] * v[j] - A2);
    float sn, cs; rsincos(phi, &sn, &cs);
    if constexpr (INIT) amp[j] = make_float2(cs, sn);
    else                amp[j] = cphase(amp[j], cs, sn);
  }
}

// psi *= ENT(i) * exp(i*rho(i)) on PAT0; rho linear in bits -> product tree:
// 1 rsincos + 31 cmul instead of 32 rsincos (R7-verified math)
__device__ __forceinline__ void applyDiagPT(float2* amp,
                                            const float* __restrict__ wb,  // b by bitpos (layer slice)
                                            const float* __restrict__ eR,  // cos(b) by bitpos
                                            const float* __restrict__ eI,  // sin(b) by bitpos
                                            float bias, int t) {
  float base = bias;
  #pragma unroll
  for (int k = 0; k < 8; k++) base += ((t >> k) & 1) ? wb[5 + k] : 0.0f;
  float2 c[NAMP];
  { float sn, cs; rsincos(base, &sn, &cs); c[0] = make_float2(cs, sn); }
  #pragma unroll
  for (int k = 0; k < 5; k++) {
    float2 e = make_float2(eR[k], eI[k]);   // PAT0 window bit k = i-bit k
    #pragma unroll
    for (int m = 0; m < (1 << k); m++) c[m | (1 << k)] = cmul(c[m], e);
  }
  #pragma unroll
  for (int j = 0; j < NAMP; j++) {
    int i = ampIndex<0>(t, j);
    float sgn = (__popc(i & (i >> 1)) & 1) ? -1.0f : 1.0f;
    amp[j] = cphase(amp[j], c[j].x * sgn, c[j].y * sgn);
  }
}

// 2nd launch_bounds arg acts as min BLOCKS/CU here (R6 evidence)
__global__ __launch_bounds__(NT, 2) void qc_kernel(
    const float* __restrict__ xin,
    const float* __restrict__ thin,
    const float* __restrict__ bin,
    float* __restrict__ out) {
  __shared__ float2 sAmp[NSLOT];       // interleaved re/im: b64 per amp
  __shared__ float gTA[65], gSA[65];   // tan(a/4-ish)=sa/(1+ca), sin(a/2) per gate l*13+q
  __shared__ float gBbit[65];          // b by [l*13 + bitpos], bitpos = 12-q
  __shared__ float eBr[65], eBi[65];   // cos(b), sin(b) by [l*13 + bitpos]
  __shared__ float wX[13], wA[13];     // -2x, -2a by bitpos
  __shared__ float cons[8];            // 0:X 1:A 2:A2 3..7:-0.5*sum b_l
  __shared__ float red[NT / 64];

  const int t = threadIdx.x;
  const int b = blockIdx.x;

  if (t < NQ) {
    float xq = xin[b * NQ + t];
    float aq = PI_F - xq;
    wX[12 - t] = -2.0f * xq;
    wA[12 - t] = -2.0f * aq;
  }
  if (t < 65) {
    float av = thin[2 * t];
    float bv = thin[2 * t + 1];
    float ca = cosf(0.5f * av);
    float sa = sinf(0.5f * av);
    gSA[t] = sa;
    gTA[t] = sa / (1.0f + ca);
    int l = t / NQ, q = t % NQ;
    int s = l * NQ + (12 - q);
    gBbit[s] = bv;
    eBr[s] = cosf(bv);
    eBi[s] = sinf(bv);
  }
  __syncthreads();
  if (t == 0) {
    float X = 0.f, A = 0.f, A2 = 0.f;
    for (int p = 0; p < NQ; p++) {
      float xq = -0.5f * wX[p], aq = -0.5f * wA[p];
      X += xq; A += aq; A2 += aq * aq;
    }
    cons[0] = X; cons[1] = A; cons[2] = A2;
    for (int l = 0; l < 5; l++) {
      float s = 0.f;
      for (int p = 0; p < NQ; p++) s += gBbit[l * NQ + p];
      cons[3 + l] = -0.5f * s;
    }
  }
  __syncthreads();

  float2 amp[NAMP];

  // ---- Pass 0 (PAT0): psi = exp(i*phi); FWHT bits 0..4
  featureDiag<0, true>(amp, wX, wA, cons, t);
  fwht_all5(amp);
  storeAmps<0>(sAmp, t, amp);
  waveFence();   // PAT0->PAT1 is wave-private

  // ---- Pass 1 (PAT1): FWHT bits 5..9
  loadAmps<1>(sAmp, t, amp);
  fwht_all5(amp);
  storeAmps<1>(sAmp, t, amp);
  __syncthreads();

  // ---- Pass 2 (PAT2): FWHT bits 10..12; second feature-map diagonal
  loadAmps<2>(sAmp, t, amp);
  fwht_bit<2>(amp); fwht_bit<3>(amp); fwht_bit<4>(amp);
  featureDiag<2, false>(amp, wX, wA, cons, t);
  storeAmps<2>(sAmp, t, amp);
  __syncthreads();

  // ---- Variational layers: Ry only; Rz(b_{l-1})+ENT fused diagonal at pass A
  float acc = 0.0f;
  for (int l = 0; l < 5; l++) {
    const int g = l * NQ;
    // pass A (PAT0): bits 0..4 (qubits 12..8)
    loadAmps<0>(sAmp, t, amp);
    if (l > 0) applyDiagPT(amp, gBbit + (l - 1) * NQ, eBr + (l - 1) * NQ,
                           eBi + (l - 1) * NQ, cons[3 + (l - 1)], t);
    applyRy<0>(amp, gTA[g + 12], gSA[g + 12]);
    applyRy<1>(amp, gTA[g + 11], gSA[g + 11]);
    applyRy<2>(amp, gTA[g + 10], gSA[g + 10]);
    applyRy<3>(amp, gTA[g + 9],  gSA[g + 9]);
    applyRy<4>(amp, gTA[g + 8],  gSA[g + 8]);
    storeAmps<0>(sAmp, t, amp);
    waveFence();   // PAT0->PAT1 is wave-private
    // pass B (PAT1): bits 5..9 (qubits 7..3)
    loadAmps<1>(sAmp, t, amp);
    applyRy<0>(amp, gTA[g + 7], gSA[g + 7]);
    applyRy<1>(amp, gTA[g + 6], gSA[g + 6]);
    applyRy<2>(amp, gTA[g + 5], gSA[g + 5]);
    applyRy<3>(amp, gTA[g + 4], gSA[g + 4]);
    applyRy<4>(amp, gTA[g + 3], gSA[g + 3]);
    storeAmps<1>(sAmp, t, amp);
    __syncthreads();
    // pass C (PAT2): bits 10..12 (qubits 2..0); last layer fuses readout
    loadAmps<2>(sAmp, t, amp);
    applyRy<2>(amp, gTA[g + 2], gSA[g + 2]);
    applyRy<3>(amp, gTA[g + 1], gSA[g + 1]);
    applyRy<4>(amp, gTA[g + 0], gSA[g + 0]);
    if (l < 4) {
      storeAmps<2>(sAmp, t, amp);
      __syncthreads();
    } else {
      // trailing Rz is diagonal -> invisible in |psi|^2; readout here
      #pragma unroll
      for (int j = 0; j < NAMP; j++) {
        int i = ampIndex<2>(t, j);
        float p2 = fmaf(amp[j].x, amp[j].x, amp[j].y * amp[j].y);
        acc += (__popc(i) & 1) ? -p2 : p2;
      }
    }
  }

  // block reduction (raw scale 2^26)
  #pragma unroll
  for (int off = 32; off > 0; off >>= 1) acc += __shfl_down(acc, off, 64);
  if ((t & 63) == 0) red[t >> 6] = acc;
  __syncthreads();
  if (t == 0) {
    float total = red[0] + red[1] + red[2] + red[3];
    float logit = total * (1.0f / 67108864.0f) + bin[0];
    out[b * 2 + 0] = -logit;
    out[b * 2 + 1] = logit;
  }
}

extern "C" void kernel_launch(void* const* d_in, const int* in_sizes, int n_in,
                              void* d_out, int out_size, void* d_ws, size_t ws_size,
                              hipStream_t stream) {
  const float* x  = (const float*)d_in[0];
  const float* th = (const float*)d_in[1];
  const float* bi = (const float*)d_in[2];
  float* out = (float*)d_out;
  int B = in_sizes[0] / NQ;   // 512
  qc_kernel<<<B, NT, 0, stream>>>(x, th, bi, out);
}